// Round 1
// baseline (468.202 us; speedup 1.0000x reference)
//
#include <hip/hip_runtime.h>

#define T_TOKENS 8192
#define DMODEL   1024
#define NEXP     8

#define BM 128   // tokens per tile
#define BN 128   // features per tile
#define BK 64    // k per step

typedef float f32x4  __attribute__((ext_vector_type(4)));
typedef short short8 __attribute__((ext_vector_type(8)));

__device__ __forceinline__ unsigned short f32_to_bf16(float f) {
    unsigned int u = __builtin_bit_cast(unsigned int, f);
    unsigned int r = 0x7FFFu + ((u >> 16) & 1u);
    return (unsigned short)((u + r) >> 16);
}

// ---------------------------------------------------------------------------
// Kernel 1: We [E][d][f] fp32  ->  we_t [E][f][d] bf16 (LDS-tiled transpose)
// ---------------------------------------------------------------------------
__global__ __launch_bounds__(256)
void we_transpose(const float* __restrict__ We, unsigned short* __restrict__ wt) {
    __shared__ unsigned short tile[64][72];
    const int e  = blockIdx.z;
    const int d0 = blockIdx.x * 64;
    const int f0 = blockIdx.y * 64;
    const float* src = We + ((size_t)e * DMODEL + d0) * DMODEL + f0;
    #pragma unroll
    for (int i = 0; i < 16; ++i) {
        int idx = i * 256 + threadIdx.x;
        int dl = idx >> 6, fl = idx & 63;
        tile[fl][dl] = f32_to_bf16(src[(size_t)dl * DMODEL + fl]);
    }
    __syncthreads();
    unsigned short* dst = wt + ((size_t)e * DMODEL + f0) * DMODEL + d0;
    #pragma unroll
    for (int i = 0; i < 16; ++i) {
        int idx = i * 256 + threadIdx.x;
        int fl = idx >> 6, dl = idx & 63;
        dst[(size_t)fl * DMODEL + dl] = tile[fl][dl];
    }
}

// ---------------------------------------------------------------------------
// Kernel 2: gating (fp32 logits, top-2, compaction) + x fp32->bf16 convert.
// One wave per token; 4 tokens per 256-thread block.
// ---------------------------------------------------------------------------
__global__ __launch_bounds__(256)
void gating(const float* __restrict__ x, const float* __restrict__ Wg,
            unsigned short* __restrict__ xb,
            int* __restrict__ counts, int* __restrict__ toks,
            float* __restrict__ wgts) {
    const int wave = threadIdx.x >> 6;
    const int lane = threadIdx.x & 63;
    const int t = blockIdx.x * 4 + wave;

    float lg[8];
    #pragma unroll
    for (int e = 0; e < 8; ++e) lg[e] = 0.0f;

    const float* xr = x + (size_t)t * DMODEL;
    unsigned short* xo = xb + (size_t)t * DMODEL;

    #pragma unroll
    for (int j = 0; j < 4; ++j) {
        const int d = j * 256 + lane * 4;
        float4 xv = *reinterpret_cast<const float4*>(xr + d);
        ushort4 o;
        o.x = f32_to_bf16(xv.x);
        o.y = f32_to_bf16(xv.y);
        o.z = f32_to_bf16(xv.z);
        o.w = f32_to_bf16(xv.w);
        *reinterpret_cast<ushort4*>(xo + d) = o;
        const float xs[4] = {xv.x, xv.y, xv.z, xv.w};
        #pragma unroll
        for (int c = 0; c < 4; ++c) {
            const float* wr = Wg + (size_t)(d + c) * 8;
            #pragma unroll
            for (int e = 0; e < 8; ++e) lg[e] += xs[c] * wr[e];
        }
    }
    // butterfly reduce across the 64-lane wave
    #pragma unroll
    for (int off = 1; off < 64; off <<= 1) {
        #pragma unroll
        for (int e = 0; e < 8; ++e) lg[e] += __shfl_xor(lg[e], off);
    }

    if (lane == 0) {
        int i1 = 0; float v1 = lg[0];
        #pragma unroll
        for (int e = 1; e < 8; ++e) if (lg[e] > v1) { v1 = lg[e]; i1 = e; }
        int i2 = -1; float v2 = -1e30f;
        #pragma unroll
        for (int e = 0; e < 8; ++e) if (e != i1 && lg[e] > v2) { v2 = lg[e]; i2 = e; }
        const float w1 = 1.0f / (1.0f + __expf(v2 - v1));
        const float w2 = 1.0f - w1;
        int p1 = atomicAdd(&counts[i1], 1);
        toks[i1 * T_TOKENS + p1] = t;
        wgts[i1 * T_TOKENS + p1] = w1;
        int p2 = atomicAdd(&counts[i2], 1);
        toks[i2 * T_TOKENS + p2] = t;
        wgts[i2 * T_TOKENS + p2] = w2;
    }
}

// ---------------------------------------------------------------------------
// Kernel 3: per-expert gather-GEMM.  Computes C^T tile:
//   D[f][p] = sum_k we_t[e][f][k] * x[tok[p]][k]   (MFMA A=we_t rows, B=x rows)
// then epilogue relu(acc + be) * w -> atomicAdd into y[tok][f].
// LDS tiles [128][64] bf16, XOR-swizzled via pre-swizzled global source
// (global_load_lds writes linearly: wave-uniform base + lane*16).
// ---------------------------------------------------------------------------
__global__ __launch_bounds__(256)
void expert_gemm(const unsigned short* __restrict__ xb,
                 const unsigned short* __restrict__ wt,
                 const float* __restrict__ be,
                 const int* __restrict__ counts,
                 const int* __restrict__ toks,
                 const float* __restrict__ wgts,
                 float* __restrict__ y) {
    const int e   = blockIdx.z;
    const int cnt = counts[e];
    const int p0  = blockIdx.x * BM;
    if (p0 >= cnt) return;
    const int f0  = blockIdx.y * BN;

    __shared__ unsigned short lds_w[BN * BK];  // [f][k], swizzled
    __shared__ unsigned short lds_x[BM * BK];  // [p][k], swizzled
    __shared__ int   tok_s[BM];
    __shared__ float wgt_s[BM];

    const int tid  = threadIdx.x;
    const int wave = tid >> 6;
    const int lane = tid & 63;

    if (tid < BM) {
        int p = p0 + tid;
        if (p < cnt) {
            tok_s[tid] = toks[e * T_TOKENS + p];
            wgt_s[tid] = wgts[e * T_TOKENS + p];
        } else {
            tok_s[tid] = 0;
            wgt_s[tid] = 0.0f;
        }
    }
    __syncthreads();

    // Per-lane staging source addresses (constant across K; add k0*2 per step).
    // Instruction q = wave*4+s covers rows q*8 .. q*8+7 of a [128][64]bf16 tile
    // (128 B/row, 8 lanes per row, 16 B per lane).
    const char* wsrc[4];
    const char* xsrc[4];
    #pragma unroll
    for (int s = 0; s < 4; ++s) {
        const int q    = wave * 4 + s;
        const int row  = q * 8 + (lane >> 3);
        const int scol = ((lane & 7) << 4) ^ ((row & 7) << 4);  // pre-swizzled
        wsrc[s] = (const char*)wt + ((size_t)(e * DMODEL + f0 + row) * DMODEL) * 2 + scol;
        xsrc[s] = (const char*)xb + ((size_t)tok_s[row] * DMODEL) * 2 + scol;
    }

    f32x4 acc[4][4] = {};

    const int wf = (wave & 1) * 64;   // feature sub-block of this wave
    const int wp = (wave >> 1) * 64;  // token sub-block of this wave

    for (int k0 = 0; k0 < DMODEL; k0 += BK) {
        #pragma unroll
        for (int s = 0; s < 4; ++s) {
            __builtin_amdgcn_global_load_lds(
                (const __attribute__((address_space(1))) void*)(wsrc[s] + (size_t)k0 * 2),
                (__attribute__((address_space(3))) void*)((char*)lds_w + (wave * 4 + s) * 1024),
                16, 0, 0);
            __builtin_amdgcn_global_load_lds(
                (const __attribute__((address_space(1))) void*)(xsrc[s] + (size_t)k0 * 2),
                (__attribute__((address_space(3))) void*)((char*)lds_x + (wave * 4 + s) * 1024),
                16, 0, 0);
        }
        __syncthreads();

        #pragma unroll
        for (int kk = 0; kk < 2; ++kk) {
            short8 afr[4], bfr[4];
            #pragma unroll
            for (int mi = 0; mi < 4; ++mi) {
                const int row = wf + mi * 16 + (lane & 15);
                const int kb  = (kk * 64 + ((lane >> 4) << 4)) ^ ((row & 7) << 4);
                afr[mi] = *(const short8*)((const char*)lds_w + row * 128 + kb);
            }
            #pragma unroll
            for (int ni = 0; ni < 4; ++ni) {
                const int row = wp + ni * 16 + (lane & 15);
                const int kb  = (kk * 64 + ((lane >> 4) << 4)) ^ ((row & 7) << 4);
                bfr[ni] = *(const short8*)((const char*)lds_x + row * 128 + kb);
            }
            #pragma unroll
            for (int mi = 0; mi < 4; ++mi)
                #pragma unroll
                for (int ni = 0; ni < 4; ++ni)
                    asm("v_mfma_f32_16x16x32_bf16 %0, %1, %2, %0"
                        : "+v"(acc[mi][ni])
                        : "v"(afr[mi]), "v"(bfr[ni]));
        }
        __syncthreads();
    }

    // Epilogue: lane holds D[f][p] frag: f = (lane>>4)*4 + r, p = lane&15.
    #pragma unroll
    for (int ni = 0; ni < 4; ++ni) {
        const int pl = wp + ni * 16 + (lane & 15);
        const int p  = p0 + pl;
        if (p >= cnt) continue;
        const int   t = tok_s[pl];
        const float w = wgt_s[pl];
        float* yr = y + (size_t)t * DMODEL + f0 + wf;
        #pragma unroll
        for (int mi = 0; mi < 4; ++mi) {
            const int fb = mi * 16 + ((lane >> 4) << 2);
            const float* ber = be + (size_t)e * DMODEL + f0 + wf + fb;
            #pragma unroll
            for (int r = 0; r < 4; ++r) {
                float v = acc[mi][ni][r] + ber[r];
                v = v > 0.0f ? v : 0.0f;
                atomicAdd(&yr[fb + r], v * w);
            }
        }
    }
}

// ---------------------------------------------------------------------------
extern "C" void kernel_launch(void* const* d_in, const int* in_sizes, int n_in,
                              void* d_out, int out_size, void* d_ws, size_t ws_size,
                              hipStream_t stream) {
    (void)in_sizes; (void)n_in; (void)out_size; (void)ws_size;
    const float* x  = (const float*)d_in[0];
    const float* Wg = (const float*)d_in[1];
    const float* We = (const float*)d_in[2];
    const float* be = (const float*)d_in[3];
    float* y = (float*)d_out;

    char* ws = (char*)d_ws;
    unsigned short* xb     = (unsigned short*)(ws);                      // 16 MB
    unsigned short* wt     = (unsigned short*)(ws + (16u << 20));        // 16 MB
    int*            counts = (int*)(ws + (32u << 20));                   // 256 B
    int*            toks   = (int*)(ws + (32u << 20) + 256);             // 256 KB
    float*          wgts   = (float*)(ws + (32u << 20) + 256 + NEXP * T_TOKENS * 4);

    hipMemsetAsync(counts, 0, 256, stream);
    hipMemsetAsync(y, 0, (size_t)T_TOKENS * DMODEL * sizeof(float), stream);

    we_transpose<<<dim3(DMODEL / 64, DMODEL / 64, NEXP), 256, 0, stream>>>(We, wt);
    gating<<<dim3(T_TOKENS / 4), 256, 0, stream>>>(x, Wg, xb, counts, toks, wgts);
    expert_gemm<<<dim3(T_TOKENS / BM, DMODEL / BN, NEXP), 256, 0, stream>>>(
        xb, wt, be, counts, toks, wgts, y);
}

// Round 2
// 312.028 us; speedup vs baseline: 1.5005x; 1.5005x over previous
//
#include <hip/hip_runtime.h>

#define T_TOKENS 8192
#define DMODEL   1024
#define NEXP     8

#define BM 128   // tokens per tile
#define BN 128   // features per tile
#define BK 64    // k per step

typedef float f32x4  __attribute__((ext_vector_type(4)));
typedef short short8 __attribute__((ext_vector_type(8)));

__device__ __forceinline__ unsigned short f32_to_bf16(float f) {
    unsigned int u = __builtin_bit_cast(unsigned int, f);
    unsigned int r = 0x7FFFu + ((u >> 16) & 1u);
    return (unsigned short)((u + r) >> 16);
}

// ---------------------------------------------------------------------------
// Kernel 1: We [E][d][f] fp32  ->  we_t [E][f][d] bf16 (LDS-tiled transpose)
// ---------------------------------------------------------------------------
__global__ __launch_bounds__(256)
void we_transpose(const float* __restrict__ We, unsigned short* __restrict__ wt) {
    __shared__ unsigned short tile[64][72];
    const int e  = blockIdx.z;
    const int d0 = blockIdx.x * 64;
    const int f0 = blockIdx.y * 64;
    const float* src = We + ((size_t)e * DMODEL + d0) * DMODEL + f0;
    #pragma unroll
    for (int i = 0; i < 16; ++i) {
        int idx = i * 256 + threadIdx.x;
        int dl = idx >> 6, fl = idx & 63;
        tile[fl][dl] = f32_to_bf16(src[(size_t)dl * DMODEL + fl]);
    }
    __syncthreads();
    unsigned short* dst = wt + ((size_t)e * DMODEL + f0) * DMODEL + d0;
    #pragma unroll
    for (int i = 0; i < 16; ++i) {
        int idx = i * 256 + threadIdx.x;
        int fl = idx >> 6, dl = idx & 63;
        dst[(size_t)fl * DMODEL + dl] = tile[fl][dl];
    }
}

// ---------------------------------------------------------------------------
// Kernel 2: gating (fp32 logits, top-2, compaction) + x fp32->bf16 convert.
// One wave per token; 4 tokens per 256-thread block. Also records, per token,
// the two partial-row indices (e*T + p) for the combine kernel.
// ---------------------------------------------------------------------------
__global__ __launch_bounds__(256)
void gating(const float* __restrict__ x, const float* __restrict__ Wg,
            unsigned short* __restrict__ xb,
            int* __restrict__ counts, int* __restrict__ toks,
            float* __restrict__ wgts, int* __restrict__ rows) {
    const int wave = threadIdx.x >> 6;
    const int lane = threadIdx.x & 63;
    const int t = blockIdx.x * 4 + wave;

    float lg[8];
    #pragma unroll
    for (int e = 0; e < 8; ++e) lg[e] = 0.0f;

    const float* xr = x + (size_t)t * DMODEL;
    unsigned short* xo = xb + (size_t)t * DMODEL;

    #pragma unroll
    for (int j = 0; j < 4; ++j) {
        const int d = j * 256 + lane * 4;
        float4 xv = *reinterpret_cast<const float4*>(xr + d);
        ushort4 o;
        o.x = f32_to_bf16(xv.x);
        o.y = f32_to_bf16(xv.y);
        o.z = f32_to_bf16(xv.z);
        o.w = f32_to_bf16(xv.w);
        *reinterpret_cast<ushort4*>(xo + d) = o;
        const float xs[4] = {xv.x, xv.y, xv.z, xv.w};
        #pragma unroll
        for (int c = 0; c < 4; ++c) {
            const float* wr = Wg + (size_t)(d + c) * 8;
            #pragma unroll
            for (int e = 0; e < 8; ++e) lg[e] += xs[c] * wr[e];
        }
    }
    // butterfly reduce across the 64-lane wave
    #pragma unroll
    for (int off = 1; off < 64; off <<= 1) {
        #pragma unroll
        for (int e = 0; e < 8; ++e) lg[e] += __shfl_xor(lg[e], off);
    }

    if (lane == 0) {
        int i1 = 0; float v1 = lg[0];
        #pragma unroll
        for (int e = 1; e < 8; ++e) if (lg[e] > v1) { v1 = lg[e]; i1 = e; }
        int i2 = -1; float v2 = -1e30f;
        #pragma unroll
        for (int e = 0; e < 8; ++e) if (e != i1 && lg[e] > v2) { v2 = lg[e]; i2 = e; }
        const float w1 = 1.0f / (1.0f + __expf(v2 - v1));
        const float w2 = 1.0f - w1;
        int p1 = atomicAdd(&counts[i1], 1);
        toks[i1 * T_TOKENS + p1] = t;
        wgts[i1 * T_TOKENS + p1] = w1;
        int p2 = atomicAdd(&counts[i2], 1);
        toks[i2 * T_TOKENS + p2] = t;
        wgts[i2 * T_TOKENS + p2] = w2;
        rows[t * 2 + 0] = i1 * T_TOKENS + p1;
        rows[t * 2 + 1] = i2 * T_TOKENS + p2;
    }
}

// ---------------------------------------------------------------------------
// Kernel 3: per-expert gather-GEMM with double-buffered LDS prefetch.
//   D[f][p] = sum_k we_t[e][f][k] * x[tok[p]][k]
// Epilogue: hpart[e*T+p][f] = bf16( relu(acc + be) * w )  -- plain stores,
// no atomics (the old atomicAdd epilogue was 268 MB of write-through RMW
// traffic and the actual bottleneck).
// ---------------------------------------------------------------------------
__global__ __launch_bounds__(256)
void expert_gemm(const unsigned short* __restrict__ xb,
                 const unsigned short* __restrict__ wt,
                 const float* __restrict__ be,
                 const int* __restrict__ counts,
                 const int* __restrict__ toks,
                 const float* __restrict__ wgts,
                 unsigned short* __restrict__ hpart) {
    const int e   = blockIdx.z;
    const int cnt = counts[e];
    const int p0  = blockIdx.x * BM;
    if (p0 >= cnt) return;
    const int f0  = blockIdx.y * BN;

    __shared__ unsigned short lds_w[2][BN * BK];  // [f][k], swizzled
    __shared__ unsigned short lds_x[2][BM * BK];  // [p][k], swizzled
    __shared__ int   tok_s[BM];
    __shared__ float wgt_s[BM];

    const int tid  = threadIdx.x;
    const int wave = tid >> 6;
    const int lane = tid & 63;

    if (tid < BM) {
        int p = p0 + tid;
        if (p < cnt) {
            tok_s[tid] = toks[e * T_TOKENS + p];
            wgt_s[tid] = wgts[e * T_TOKENS + p];
        } else {
            tok_s[tid] = 0;
            wgt_s[tid] = 0.0f;
        }
    }
    __syncthreads();

    // Per-lane staging source addresses (constant across K; add k0*2 per step).
    // Instruction q = wave*4+s covers rows q*8 .. q*8+7 of a [128][64]bf16 tile
    // (128 B/row, 8 lanes per row, 16 B per lane). Source is pre-swizzled so
    // the linear global_load_lds write produces the XOR-swizzled LDS layout.
    const char* wsrc[4];
    const char* xsrc[4];
    #pragma unroll
    for (int s = 0; s < 4; ++s) {
        const int q    = wave * 4 + s;
        const int row  = q * 8 + (lane >> 3);
        const int scol = ((lane & 7) << 4) ^ ((row & 7) << 4);  // pre-swizzled
        wsrc[s] = (const char*)wt + ((size_t)(e * DMODEL + f0 + row) * DMODEL) * 2 + scol;
        xsrc[s] = (const char*)xb + ((size_t)tok_s[row] * DMODEL) * 2 + scol;
    }

    auto stage = [&](int buf, int k0) {
        #pragma unroll
        for (int s = 0; s < 4; ++s) {
            __builtin_amdgcn_global_load_lds(
                (const __attribute__((address_space(1))) void*)(wsrc[s] + (size_t)k0 * 2),
                (__attribute__((address_space(3))) void*)((char*)lds_w[buf] + (wave * 4 + s) * 1024),
                16, 0, 0);
            __builtin_amdgcn_global_load_lds(
                (const __attribute__((address_space(1))) void*)(xsrc[s] + (size_t)k0 * 2),
                (__attribute__((address_space(3))) void*)((char*)lds_x[buf] + (wave * 4 + s) * 1024),
                16, 0, 0);
        }
    };

    f32x4 acc[4][4] = {};

    const int wf = (wave & 1) * 64;   // feature sub-block of this wave
    const int wp = (wave >> 1) * 64;  // token sub-block of this wave

    // Prologue: stage K-tile 0 into buffer 0.
    stage(0, 0);
    __syncthreads();

    int cur = 0;
    #pragma unroll 1
    for (int t = 0; t < DMODEL / BK; ++t) {
        // Prefetch next K-tile into the other buffer; its latency hides
        // under this tile's ds_read + MFMA.
        if (t + 1 < DMODEL / BK) stage(cur ^ 1, (t + 1) * BK);

        #pragma unroll
        for (int kk = 0; kk < 2; ++kk) {
            short8 afr[4], bfr[4];
            #pragma unroll
            for (int mi = 0; mi < 4; ++mi) {
                const int row = wf + mi * 16 + (lane & 15);
                const int kb  = (kk * 64 + ((lane >> 4) << 4)) ^ ((row & 7) << 4);
                afr[mi] = *(const short8*)((const char*)lds_w[cur] + row * 128 + kb);
            }
            #pragma unroll
            for (int ni = 0; ni < 4; ++ni) {
                const int row = wp + ni * 16 + (lane & 15);
                const int kb  = (kk * 64 + ((lane >> 4) << 4)) ^ ((row & 7) << 4);
                bfr[ni] = *(const short8*)((const char*)lds_x[cur] + row * 128 + kb);
            }
            #pragma unroll
            for (int mi = 0; mi < 4; ++mi)
                #pragma unroll
                for (int ni = 0; ni < 4; ++ni)
                    asm("v_mfma_f32_16x16x32_bf16 %0, %1, %2, %0"
                        : "+v"(acc[mi][ni])
                        : "v"(afr[mi]), "v"(bfr[ni]));
        }
        __syncthreads();   // compiler drains vmcnt+lgkmcnt before s_barrier
        cur ^= 1;
    }

    // Epilogue: lane holds D[f][p] frag: f = (lane>>4)*4 + r, p = lane&15.
    // Plain bf16 stores into the compacted partial buffer.
    #pragma unroll
    for (int ni = 0; ni < 4; ++ni) {
        const int pl = wp + ni * 16 + (lane & 15);
        const int p  = p0 + pl;
        if (p >= cnt) continue;
        const float w = wgt_s[pl];
        unsigned short* hr = hpart + (size_t)(e * T_TOKENS + p) * DMODEL + f0 + wf;
        #pragma unroll
        for (int mi = 0; mi < 4; ++mi) {
            const int fb = mi * 16 + ((lane >> 4) << 2);
            const float* ber = be + (size_t)e * DMODEL + f0 + wf + fb;
            ushort4 o;
            float v0 = acc[mi][ni][0] + ber[0]; v0 = v0 > 0.f ? v0 : 0.f;
            float v1 = acc[mi][ni][1] + ber[1]; v1 = v1 > 0.f ? v1 : 0.f;
            float v2 = acc[mi][ni][2] + ber[2]; v2 = v2 > 0.f ? v2 : 0.f;
            float v3 = acc[mi][ni][3] + ber[3]; v3 = v3 > 0.f ? v3 : 0.f;
            o.x = f32_to_bf16(v0 * w);
            o.y = f32_to_bf16(v1 * w);
            o.z = f32_to_bf16(v2 * w);
            o.w = f32_to_bf16(v3 * w);
            *reinterpret_cast<ushort4*>(hr + fb) = o;
        }
    }
}

// ---------------------------------------------------------------------------
// Kernel 4: combine — y[t] = hpart[rows[t][0]] + hpart[rows[t][1]]
// One block per token, 256 threads x 4 floats. Fully coalesced, no atomics.
// ---------------------------------------------------------------------------
__global__ __launch_bounds__(256)
void combine(const unsigned short* __restrict__ hpart,
             const int* __restrict__ rows,
             float* __restrict__ y) {
    const int t = blockIdx.x;
    const int r0 = rows[t * 2 + 0];
    const int r1 = rows[t * 2 + 1];
    const int f = threadIdx.x * 4;
    ushort4 a = *reinterpret_cast<const ushort4*>(hpart + (size_t)r0 * DMODEL + f);
    ushort4 b = *reinterpret_cast<const ushort4*>(hpart + (size_t)r1 * DMODEL + f);
    float4 o;
    o.x = __builtin_bit_cast(float, (unsigned)a.x << 16) + __builtin_bit_cast(float, (unsigned)b.x << 16);
    o.y = __builtin_bit_cast(float, (unsigned)a.y << 16) + __builtin_bit_cast(float, (unsigned)b.y << 16);
    o.z = __builtin_bit_cast(float, (unsigned)a.z << 16) + __builtin_bit_cast(float, (unsigned)b.z << 16);
    o.w = __builtin_bit_cast(float, (unsigned)a.w << 16) + __builtin_bit_cast(float, (unsigned)b.w << 16);
    *reinterpret_cast<float4*>(y + (size_t)t * DMODEL + f) = o;
}

// ---------------------------------------------------------------------------
extern "C" void kernel_launch(void* const* d_in, const int* in_sizes, int n_in,
                              void* d_out, int out_size, void* d_ws, size_t ws_size,
                              hipStream_t stream) {
    (void)in_sizes; (void)n_in; (void)out_size; (void)ws_size;
    const float* x  = (const float*)d_in[0];
    const float* Wg = (const float*)d_in[1];
    const float* We = (const float*)d_in[2];
    const float* be = (const float*)d_in[3];
    float* y = (float*)d_out;

    char* ws = (char*)d_ws;
    unsigned short* xb     = (unsigned short*)(ws);                      // 16 MB
    unsigned short* wt     = (unsigned short*)(ws + (16u << 20));        // 16 MB
    int*            counts = (int*)(ws + (32u << 20));                   // 32 B
    int*            toks   = (int*)(ws + (32u << 20) + 1024);            // 256 KB
    float*          wgts   = (float*)(ws + (32u << 20) + 1024 + NEXP * T_TOKENS * 4);
    int*            rows   = (int*)(ws + (32u << 20) + 1024 + 2 * NEXP * T_TOKENS * 4);
    unsigned short* hpart  = (unsigned short*)(ws + (33u << 20));        // 2*T*D bf16 = 33.5 MB

    hipMemsetAsync(counts, 0, 1024, stream);

    we_transpose<<<dim3(DMODEL / 64, DMODEL / 64, NEXP), 256, 0, stream>>>(We, wt);
    gating<<<dim3(T_TOKENS / 4), 256, 0, stream>>>(x, Wg, xb, counts, toks, wgts, rows);
    expert_gemm<<<dim3(T_TOKENS / BM, DMODEL / BN, NEXP), 256, 0, stream>>>(
        xb, wt, be, counts, toks, wgts, hpart);
    combine<<<dim3(T_TOKENS), 256, 0, stream>>>(hpart, rows, y);
}

// Round 3
// 161.339 us; speedup vs baseline: 2.9020x; 1.9340x over previous
//
#include <hip/hip_runtime.h>

#define T_TOKENS 8192
#define DMODEL   1024
#define NEXP     8

#define BM 128   // tokens per tile
#define BN 128   // features per tile
#define BK 64    // k per step

typedef float f32x4  __attribute__((ext_vector_type(4)));
typedef short short8 __attribute__((ext_vector_type(8)));

__device__ __forceinline__ unsigned short f32_to_bf16(float f) {
    unsigned int u = __builtin_bit_cast(unsigned int, f);
    unsigned int r = 0x7FFFu + ((u >> 16) & 1u);
    return (unsigned short)((u + r) >> 16);
}

// ---------------------------------------------------------------------------
// Kernel 1: We [E][d][f] fp32  ->  we_t [E][f][d] bf16 (LDS-tiled transpose)
// ---------------------------------------------------------------------------
__global__ __launch_bounds__(256)
void we_transpose(const float* __restrict__ We, unsigned short* __restrict__ wt) {
    __shared__ unsigned short tile[64][72];
    const int e  = blockIdx.z;
    const int d0 = blockIdx.x * 64;
    const int f0 = blockIdx.y * 64;
    const float* src = We + ((size_t)e * DMODEL + d0) * DMODEL + f0;
    #pragma unroll
    for (int i = 0; i < 16; ++i) {
        int idx = i * 256 + threadIdx.x;
        int dl = idx >> 6, fl = idx & 63;
        tile[fl][dl] = f32_to_bf16(src[(size_t)dl * DMODEL + fl]);
    }
    __syncthreads();
    unsigned short* dst = wt + ((size_t)e * DMODEL + f0) * DMODEL + d0;
    #pragma unroll
    for (int i = 0; i < 16; ++i) {
        int idx = i * 256 + threadIdx.x;
        int fl = idx >> 6, dl = idx & 63;
        dst[(size_t)fl * DMODEL + dl] = tile[fl][dl];
    }
}

// ---------------------------------------------------------------------------
// Kernel 2: gating — fp32 logits + top-2 per token, NO atomics.
// One wave per token; 4 tokens per 256-thread block. Also converts x->bf16.
// Writes top_e[t] = e1 | (e2<<4)  and  top_w[t] = w1  (w2 = 1 - w1).
// ---------------------------------------------------------------------------
__global__ __launch_bounds__(256)
void gating(const float* __restrict__ x, const float* __restrict__ Wg,
            unsigned short* __restrict__ xb,
            int* __restrict__ top_e, float* __restrict__ top_w) {
    const int wave = threadIdx.x >> 6;
    const int lane = threadIdx.x & 63;
    const int t = blockIdx.x * 4 + wave;

    float lg[8];
    #pragma unroll
    for (int e = 0; e < 8; ++e) lg[e] = 0.0f;

    const float* xr = x + (size_t)t * DMODEL;
    unsigned short* xo = xb + (size_t)t * DMODEL;

    #pragma unroll
    for (int j = 0; j < 4; ++j) {
        const int d = j * 256 + lane * 4;
        float4 xv = *reinterpret_cast<const float4*>(xr + d);
        ushort4 o;
        o.x = f32_to_bf16(xv.x);
        o.y = f32_to_bf16(xv.y);
        o.z = f32_to_bf16(xv.z);
        o.w = f32_to_bf16(xv.w);
        *reinterpret_cast<ushort4*>(xo + d) = o;
        const float xs[4] = {xv.x, xv.y, xv.z, xv.w};
        #pragma unroll
        for (int c = 0; c < 4; ++c) {
            const float4 wlo = *reinterpret_cast<const float4*>(Wg + (size_t)(d + c) * 8);
            const float4 whi = *reinterpret_cast<const float4*>(Wg + (size_t)(d + c) * 8 + 4);
            lg[0] += xs[c] * wlo.x;  lg[1] += xs[c] * wlo.y;
            lg[2] += xs[c] * wlo.z;  lg[3] += xs[c] * wlo.w;
            lg[4] += xs[c] * whi.x;  lg[5] += xs[c] * whi.y;
            lg[6] += xs[c] * whi.z;  lg[7] += xs[c] * whi.w;
        }
    }
    // butterfly reduce across the 64-lane wave
    #pragma unroll
    for (int off = 1; off < 64; off <<= 1) {
        #pragma unroll
        for (int e = 0; e < 8; ++e) lg[e] += __shfl_xor(lg[e], off);
    }

    if (lane == 0) {
        int i1 = 0; float v1 = lg[0];
        #pragma unroll
        for (int e = 1; e < 8; ++e) if (lg[e] > v1) { v1 = lg[e]; i1 = e; }
        int i2 = -1; float v2 = -1e30f;
        #pragma unroll
        for (int e = 0; e < 8; ++e) if (e != i1 && lg[e] > v2) { v2 = lg[e]; i2 = e; }
        const float w1 = 1.0f / (1.0f + __expf(v2 - v1));
        top_e[t] = i1 | (i2 << 4);
        top_w[t] = w1;
    }
}

// ---------------------------------------------------------------------------
// Kernel 2b: compact — 8 blocks (one per expert). Ballot-scan prefix-sum
// compaction: zero atomics, deterministic token-ordered lists.
// ---------------------------------------------------------------------------
__global__ __launch_bounds__(256)
void compact(const int* __restrict__ top_e, const float* __restrict__ top_w,
             int* __restrict__ counts, int* __restrict__ toks,
             float* __restrict__ wgts, int* __restrict__ rows) {
    const int e    = blockIdx.x;
    const int tid  = threadIdx.x;
    const int wave = tid >> 6;
    const int lane = tid & 63;
    __shared__ int wsum[4];

    int base = 0;
    for (int t0 = 0; t0 < T_TOKENS; t0 += 256) {
        const int t  = t0 + tid;
        const int te = top_e[t];
        const int e1 = te & 15;
        const int e2 = (te >> 4) & 15;
        const bool m = (e1 == e) || (e2 == e);
        const unsigned long long b = __ballot(m);
        const int pos_in_wave = __popcll(b & ((1ull << lane) - 1ull));
        if (lane == 0) wsum[wave] = __popcll(b);
        __syncthreads();
        int woff = base;
        #pragma unroll
        for (int i = 0; i < 4; ++i) if (i < wave) woff += wsum[i];
        const int total = wsum[0] + wsum[1] + wsum[2] + wsum[3];
        if (m) {
            const int pos = woff + pos_in_wave;
            const float w1 = top_w[t];
            toks[e * T_TOKENS + pos] = t;
            wgts[e * T_TOKENS + pos] = (e1 == e) ? w1 : 1.0f - w1;
            rows[t * 2 + ((e1 == e) ? 0 : 1)] = e * T_TOKENS + pos;
        }
        base += total;
        __syncthreads();
    }
    if (tid == 0) counts[e] = base;
}

// ---------------------------------------------------------------------------
// Kernel 3: per-expert gather-GEMM with double-buffered LDS prefetch.
//   D[f][p] = sum_k we_t[e][f][k] * x[tok[p]][k]
// Epilogue: hpart[e*T+p][f] = bf16( relu(acc + be) * w )  -- plain stores.
// ---------------------------------------------------------------------------
__global__ __launch_bounds__(256)
void expert_gemm(const unsigned short* __restrict__ xb,
                 const unsigned short* __restrict__ wt,
                 const float* __restrict__ be,
                 const int* __restrict__ counts,
                 const int* __restrict__ toks,
                 const float* __restrict__ wgts,
                 unsigned short* __restrict__ hpart) {
    const int e   = blockIdx.z;
    const int cnt = counts[e];
    const int p0  = blockIdx.x * BM;
    if (p0 >= cnt) return;
    const int f0  = blockIdx.y * BN;

    __shared__ unsigned short lds_w[2][BN * BK];  // [f][k], swizzled
    __shared__ unsigned short lds_x[2][BM * BK];  // [p][k], swizzled
    __shared__ int   tok_s[BM];
    __shared__ float wgt_s[BM];

    const int tid  = threadIdx.x;
    const int wave = tid >> 6;
    const int lane = tid & 63;

    if (tid < BM) {
        int p = p0 + tid;
        if (p < cnt) {
            tok_s[tid] = toks[e * T_TOKENS + p];
            wgt_s[tid] = wgts[e * T_TOKENS + p];
        } else {
            tok_s[tid] = 0;
            wgt_s[tid] = 0.0f;
        }
    }
    __syncthreads();

    // Per-lane staging source addresses (constant across K; add k0*2 per step).
    // Instruction q = wave*4+s covers rows q*8 .. q*8+7 of a [128][64]bf16 tile
    // (128 B/row, 8 lanes per row, 16 B per lane). Source is pre-swizzled so
    // the linear global_load_lds write produces the XOR-swizzled LDS layout.
    const char* wsrc[4];
    const char* xsrc[4];
    #pragma unroll
    for (int s = 0; s < 4; ++s) {
        const int q    = wave * 4 + s;
        const int row  = q * 8 + (lane >> 3);
        const int scol = ((lane & 7) << 4) ^ ((row & 7) << 4);  // pre-swizzled
        wsrc[s] = (const char*)wt + ((size_t)(e * DMODEL + f0 + row) * DMODEL) * 2 + scol;
        xsrc[s] = (const char*)xb + ((size_t)tok_s[row] * DMODEL) * 2 + scol;
    }

    auto stage = [&](int buf, int k0) {
        #pragma unroll
        for (int s = 0; s < 4; ++s) {
            __builtin_amdgcn_global_load_lds(
                (const __attribute__((address_space(1))) void*)(wsrc[s] + (size_t)k0 * 2),
                (__attribute__((address_space(3))) void*)((char*)lds_w[buf] + (wave * 4 + s) * 1024),
                16, 0, 0);
            __builtin_amdgcn_global_load_lds(
                (const __attribute__((address_space(1))) void*)(xsrc[s] + (size_t)k0 * 2),
                (__attribute__((address_space(3))) void*)((char*)lds_x[buf] + (wave * 4 + s) * 1024),
                16, 0, 0);
        }
    };

    f32x4 acc[4][4] = {};

    const int wf = (wave & 1) * 64;   // feature sub-block of this wave
    const int wp = (wave >> 1) * 64;  // token sub-block of this wave

    stage(0, 0);
    __syncthreads();

    int cur = 0;
    #pragma unroll 1
    for (int t = 0; t < DMODEL / BK; ++t) {
        if (t + 1 < DMODEL / BK) stage(cur ^ 1, (t + 1) * BK);

        #pragma unroll
        for (int kk = 0; kk < 2; ++kk) {
            short8 afr[4], bfr[4];
            #pragma unroll
            for (int mi = 0; mi < 4; ++mi) {
                const int row = wf + mi * 16 + (lane & 15);
                const int kb  = (kk * 64 + ((lane >> 4) << 4)) ^ ((row & 7) << 4);
                afr[mi] = *(const short8*)((const char*)lds_w[cur] + row * 128 + kb);
            }
            #pragma unroll
            for (int ni = 0; ni < 4; ++ni) {
                const int row = wp + ni * 16 + (lane & 15);
                const int kb  = (kk * 64 + ((lane >> 4) << 4)) ^ ((row & 7) << 4);
                bfr[ni] = *(const short8*)((const char*)lds_x[cur] + row * 128 + kb);
            }
            #pragma unroll
            for (int mi = 0; mi < 4; ++mi)
                #pragma unroll
                for (int ni = 0; ni < 4; ++ni)
                    asm("v_mfma_f32_16x16x32_bf16 %0, %1, %2, %0"
                        : "+v"(acc[mi][ni])
                        : "v"(afr[mi]), "v"(bfr[ni]));
        }
        __syncthreads();
        cur ^= 1;
    }

    // Epilogue: lane holds D[f][p] frag: f = (lane>>4)*4 + r, p = lane&15.
    #pragma unroll
    for (int ni = 0; ni < 4; ++ni) {
        const int pl = wp + ni * 16 + (lane & 15);
        const int p  = p0 + pl;
        if (p >= cnt) continue;
        const float w = wgt_s[pl];
        unsigned short* hr = hpart + (size_t)(e * T_TOKENS + p) * DMODEL + f0 + wf;
        #pragma unroll
        for (int mi = 0; mi < 4; ++mi) {
            const int fb = mi * 16 + ((lane >> 4) << 2);
            const float* ber = be + (size_t)e * DMODEL + f0 + wf + fb;
            ushort4 o;
            float v0 = acc[mi][ni][0] + ber[0]; v0 = v0 > 0.f ? v0 : 0.f;
            float v1 = acc[mi][ni][1] + ber[1]; v1 = v1 > 0.f ? v1 : 0.f;
            float v2 = acc[mi][ni][2] + ber[2]; v2 = v2 > 0.f ? v2 : 0.f;
            float v3 = acc[mi][ni][3] + ber[3]; v3 = v3 > 0.f ? v3 : 0.f;
            o.x = f32_to_bf16(v0 * w);
            o.y = f32_to_bf16(v1 * w);
            o.z = f32_to_bf16(v2 * w);
            o.w = f32_to_bf16(v3 * w);
            *reinterpret_cast<ushort4*>(hr + fb) = o;
        }
    }
}

// ---------------------------------------------------------------------------
// Kernel 4: combine — y[t] = hpart[rows[t][0]] + hpart[rows[t][1]]
// ---------------------------------------------------------------------------
__global__ __launch_bounds__(256)
void combine(const unsigned short* __restrict__ hpart,
             const int* __restrict__ rows,
             float* __restrict__ y) {
    const int t = blockIdx.x;
    const int r0 = rows[t * 2 + 0];
    const int r1 = rows[t * 2 + 1];
    const int f = threadIdx.x * 4;
    ushort4 a = *reinterpret_cast<const ushort4*>(hpart + (size_t)r0 * DMODEL + f);
    ushort4 b = *reinterpret_cast<const ushort4*>(hpart + (size_t)r1 * DMODEL + f);
    float4 o;
    o.x = __builtin_bit_cast(float, (unsigned)a.x << 16) + __builtin_bit_cast(float, (unsigned)b.x << 16);
    o.y = __builtin_bit_cast(float, (unsigned)a.y << 16) + __builtin_bit_cast(float, (unsigned)b.y << 16);
    o.z = __builtin_bit_cast(float, (unsigned)a.z << 16) + __builtin_bit_cast(float, (unsigned)b.z << 16);
    o.w = __builtin_bit_cast(float, (unsigned)a.w << 16) + __builtin_bit_cast(float, (unsigned)b.w << 16);
    *reinterpret_cast<float4*>(y + (size_t)t * DMODEL + f) = o;
}

// ---------------------------------------------------------------------------
extern "C" void kernel_launch(void* const* d_in, const int* in_sizes, int n_in,
                              void* d_out, int out_size, void* d_ws, size_t ws_size,
                              hipStream_t stream) {
    (void)in_sizes; (void)n_in; (void)out_size; (void)ws_size;
    const float* x  = (const float*)d_in[0];
    const float* Wg = (const float*)d_in[1];
    const float* We = (const float*)d_in[2];
    const float* be = (const float*)d_in[3];
    float* y = (float*)d_out;

    char* ws = (char*)d_ws;
    unsigned short* xb     = (unsigned short*)(ws);                       // 16 MB
    unsigned short* wt     = (unsigned short*)(ws + (16u << 20));         // 16 MB
    size_t off = (32u << 20);
    int*            counts = (int*)(ws + off);            off += 1024;
    int*            toks   = (int*)(ws + off);            off += (size_t)NEXP * T_TOKENS * 4;
    float*          wgts   = (float*)(ws + off);          off += (size_t)NEXP * T_TOKENS * 4;
    int*            rows   = (int*)(ws + off);            off += (size_t)T_TOKENS * 2 * 4;
    int*            top_e  = (int*)(ws + off);            off += (size_t)T_TOKENS * 4;
    float*          top_w  = (float*)(ws + off);
    unsigned short* hpart  = (unsigned short*)(ws + (34u << 20));         // 32 MB

    we_transpose<<<dim3(DMODEL / 64, DMODEL / 64, NEXP), 256, 0, stream>>>(We, wt);
    gating<<<dim3(T_TOKENS / 4), 256, 0, stream>>>(x, Wg, xb, top_e, top_w);
    compact<<<dim3(NEXP), 256, 0, stream>>>(top_e, top_w, counts, toks, wgts, rows);
    expert_gemm<<<dim3(T_TOKENS / BM, DMODEL / BN, NEXP), 256, 0, stream>>>(
        xb, wt, be, counts, toks, wgts, hpart);
    combine<<<dim3(T_TOKENS), 256, 0, stream>>>(hpart, rows, y);
}

// Round 4
// 144.641 us; speedup vs baseline: 3.2370x; 1.1154x over previous
//
#include <hip/hip_runtime.h>

#define T_TOKENS 8192
#define DMODEL   1024
#define NEXP     8

#define BM 128   // tokens per tile
#define BN 128   // features per tile
#define BK 64    // k per step
#define NSTEP (DMODEL / BK)

typedef float f32x4  __attribute__((ext_vector_type(4)));
typedef short short8 __attribute__((ext_vector_type(8)));

__device__ __forceinline__ unsigned short f32_to_bf16(float f) {
    unsigned int u = __builtin_bit_cast(unsigned int, f);
    unsigned int r = 0x7FFFu + ((u >> 16) & 1u);
    return (unsigned short)((u + r) >> 16);
}

// ---------------------------------------------------------------------------
// Kernel 1: We [E][d][f] fp32  ->  we_t [E][f][d] bf16 (LDS-tiled transpose)
// ---------------------------------------------------------------------------
__global__ __launch_bounds__(256)
void we_transpose(const float* __restrict__ We, unsigned short* __restrict__ wt) {
    __shared__ unsigned short tile[64][72];
    const int e  = blockIdx.z;
    const int d0 = blockIdx.x * 64;
    const int f0 = blockIdx.y * 64;
    const float* src = We + ((size_t)e * DMODEL + d0) * DMODEL + f0;
    #pragma unroll
    for (int i = 0; i < 16; ++i) {
        int idx = i * 256 + threadIdx.x;
        int dl = idx >> 6, fl = idx & 63;
        tile[fl][dl] = f32_to_bf16(src[(size_t)dl * DMODEL + fl]);
    }
    __syncthreads();
    unsigned short* dst = wt + ((size_t)e * DMODEL + f0) * DMODEL + d0;
    #pragma unroll
    for (int i = 0; i < 16; ++i) {
        int idx = i * 256 + threadIdx.x;
        int fl = idx >> 6, dl = idx & 63;
        dst[(size_t)fl * DMODEL + dl] = tile[fl][dl];
    }
}

// ---------------------------------------------------------------------------
// Kernel 2: gating — fp32 logits + top-2 per token, NO atomics.
// Writes top_e[t] = e1 | (e2<<4) and top_w[t] = w1 (w2 = 1 - w1); x -> bf16.
// ---------------------------------------------------------------------------
__global__ __launch_bounds__(256)
void gating(const float* __restrict__ x, const float* __restrict__ Wg,
            unsigned short* __restrict__ xb,
            int* __restrict__ top_e, float* __restrict__ top_w) {
    const int wave = threadIdx.x >> 6;
    const int lane = threadIdx.x & 63;
    const int t = blockIdx.x * 4 + wave;

    float lg[8];
    #pragma unroll
    for (int e = 0; e < 8; ++e) lg[e] = 0.0f;

    const float* xr = x + (size_t)t * DMODEL;
    unsigned short* xo = xb + (size_t)t * DMODEL;

    #pragma unroll
    for (int j = 0; j < 4; ++j) {
        const int d = j * 256 + lane * 4;
        float4 xv = *reinterpret_cast<const float4*>(xr + d);
        ushort4 o;
        o.x = f32_to_bf16(xv.x);
        o.y = f32_to_bf16(xv.y);
        o.z = f32_to_bf16(xv.z);
        o.w = f32_to_bf16(xv.w);
        *reinterpret_cast<ushort4*>(xo + d) = o;
        const float xs[4] = {xv.x, xv.y, xv.z, xv.w};
        #pragma unroll
        for (int c = 0; c < 4; ++c) {
            const float4 wlo = *reinterpret_cast<const float4*>(Wg + (size_t)(d + c) * 8);
            const float4 whi = *reinterpret_cast<const float4*>(Wg + (size_t)(d + c) * 8 + 4);
            lg[0] += xs[c] * wlo.x;  lg[1] += xs[c] * wlo.y;
            lg[2] += xs[c] * wlo.z;  lg[3] += xs[c] * wlo.w;
            lg[4] += xs[c] * whi.x;  lg[5] += xs[c] * whi.y;
            lg[6] += xs[c] * whi.z;  lg[7] += xs[c] * whi.w;
        }
    }
    #pragma unroll
    for (int off = 1; off < 64; off <<= 1) {
        #pragma unroll
        for (int e = 0; e < 8; ++e) lg[e] += __shfl_xor(lg[e], off);
    }

    if (lane == 0) {
        int i1 = 0; float v1 = lg[0];
        #pragma unroll
        for (int e = 1; e < 8; ++e) if (lg[e] > v1) { v1 = lg[e]; i1 = e; }
        int i2 = -1; float v2 = -1e30f;
        #pragma unroll
        for (int e = 0; e < 8; ++e) if (e != i1 && lg[e] > v2) { v2 = lg[e]; i2 = e; }
        const float w1 = 1.0f / (1.0f + __expf(v2 - v1));
        top_e[t] = i1 | (i2 << 4);
        top_w[t] = w1;
    }
}

// ---------------------------------------------------------------------------
// Kernel 2b: compact_count — grid (E, 32). Block (e,c) counts matches of
// expert e among tokens [c*256, c*256+256). No atomics.
// ---------------------------------------------------------------------------
__global__ __launch_bounds__(256)
void compact_count(const int* __restrict__ top_e, int* __restrict__ chunk_cnt) {
    const int e = blockIdx.x, c = blockIdx.y;
    const int t = c * 256 + threadIdx.x;
    const int te = top_e[t];
    const bool m = ((te & 15) == e) || (((te >> 4) & 15) == e);
    __shared__ int ws[4];
    unsigned long long b = __ballot(m);
    if ((threadIdx.x & 63) == 0) ws[threadIdx.x >> 6] = __popcll(b);
    __syncthreads();
    if (threadIdx.x == 0)
        chunk_cnt[e * 32 + c] = ws[0] + ws[1] + ws[2] + ws[3];
}

// ---------------------------------------------------------------------------
// Kernel 2c: compact_scatter — grid (E, 32). Inline exclusive prefix over
// chunk counts (32 values from LDS), then ballot-ordered scatter.
// Deterministic token-ordered lists, zero atomics.
// ---------------------------------------------------------------------------
__global__ __launch_bounds__(256)
void compact_scatter(const int* __restrict__ top_e, const float* __restrict__ top_w,
                     const int* __restrict__ chunk_cnt,
                     int* __restrict__ counts, int* __restrict__ toks,
                     float* __restrict__ wgts, int* __restrict__ rows) {
    const int e    = blockIdx.x;
    const int c    = blockIdx.y;
    const int tid  = threadIdx.x;
    const int wave = tid >> 6;
    const int lane = tid & 63;

    __shared__ int sc[32];
    __shared__ int ws[4];
    if (tid < 32) sc[tid] = chunk_cnt[e * 32 + tid];

    const int t  = c * 256 + tid;
    const int te = top_e[t];
    const int e1 = te & 15;
    const int e2 = (te >> 4) & 15;
    const bool m = (e1 == e) || (e2 == e);
    const unsigned long long b = __ballot(m);
    const int pos_in_wave = __popcll(b & ((1ull << lane) - 1ull));
    if (lane == 0) ws[wave] = __popcll(b);
    __syncthreads();

    int base = 0;
    for (int i = 0; i < c; ++i) base += sc[i];   // LDS broadcast reads
    int woff = base;
    #pragma unroll
    for (int i = 0; i < 4; ++i) if (i < wave) woff += ws[i];

    if (m) {
        const int pos = woff + pos_in_wave;
        const float w1 = top_w[t];
        toks[e * T_TOKENS + pos] = t;
        wgts[e * T_TOKENS + pos] = (e1 == e) ? w1 : 1.0f - w1;
        rows[t * 2 + ((e1 == e) ? 0 : 1)] = e * T_TOKENS + pos;
    }
    if (c == 31 && tid == 0)
        counts[e] = base + ws[0] + ws[1] + ws[2] + ws[3];
}

// ---------------------------------------------------------------------------
// Kernel 3: per-expert gather-GEMM, counted-vmcnt double-buffer pipeline.
//   D[f][p] = sum_k we_t[e][f][k] * x[tok[p]][k]
// Per K-step: compute(cur) | barrier | stage(cur, t+2) | vmcnt(8) | barrier.
// vmcnt(8) leaves tile t+2's 8 loads in flight across the barrier; tile t+1's
// loads had a full iteration of compute to land (vs the old __syncthreads
// which drained vmcnt(0) and exposed the full load latency every step).
// ---------------------------------------------------------------------------
__global__ __launch_bounds__(256)
void expert_gemm(const unsigned short* __restrict__ xb,
                 const unsigned short* __restrict__ wt,
                 const float* __restrict__ be,
                 const int* __restrict__ counts,
                 const int* __restrict__ toks,
                 const float* __restrict__ wgts,
                 unsigned short* __restrict__ hpart) {
    const int e   = blockIdx.z;
    const int cnt = counts[e];
    const int p0  = blockIdx.x * BM;
    if (p0 >= cnt) return;
    const int f0  = blockIdx.y * BN;

    __shared__ unsigned short lds_w[2][BN * BK];  // [f][k], swizzled
    __shared__ unsigned short lds_x[2][BM * BK];  // [p][k], swizzled
    __shared__ int   tok_s[BM];
    __shared__ float wgt_s[BM];

    const int tid  = threadIdx.x;
    const int wave = tid >> 6;
    const int lane = tid & 63;

    if (tid < BM) {
        int p = p0 + tid;
        if (p < cnt) {
            tok_s[tid] = toks[e * T_TOKENS + p];
            wgt_s[tid] = wgts[e * T_TOKENS + p];
        } else {
            tok_s[tid] = 0;
            wgt_s[tid] = 0.0f;
        }
    }
    __syncthreads();

    // Per-lane staging sources, pre-swizzled so the linear global_load_lds
    // write produces the XOR-swizzled LDS layout.
    const char* wsrc[4];
    const char* xsrc[4];
    #pragma unroll
    for (int s = 0; s < 4; ++s) {
        const int q    = wave * 4 + s;
        const int row  = q * 8 + (lane >> 3);
        const int scol = ((lane & 7) << 4) ^ ((row & 7) << 4);
        wsrc[s] = (const char*)wt + ((size_t)(e * DMODEL + f0 + row) * DMODEL) * 2 + scol;
        xsrc[s] = (const char*)xb + ((size_t)tok_s[row] * DMODEL) * 2 + scol;
    }

    auto stage = [&](int buf, int k0) {
        #pragma unroll
        for (int s = 0; s < 4; ++s) {
            __builtin_amdgcn_global_load_lds(
                (const __attribute__((address_space(1))) void*)(wsrc[s] + (size_t)k0 * 2),
                (__attribute__((address_space(3))) void*)((char*)lds_w[buf] + (wave * 4 + s) * 1024),
                16, 0, 0);
            __builtin_amdgcn_global_load_lds(
                (const __attribute__((address_space(1))) void*)(xsrc[s] + (size_t)k0 * 2),
                (__attribute__((address_space(3))) void*)((char*)lds_x[buf] + (wave * 4 + s) * 1024),
                16, 0, 0);
        }
    };

    f32x4 acc[4][4] = {};

    const int wf = (wave & 1) * 64;   // feature sub-block of this wave
    const int wp = (wave >> 1) * 64;  // token sub-block of this wave

    // Prologue: tile 0 ready; tile 1 in flight.
    stage(0, 0);
    asm volatile("s_waitcnt vmcnt(0)" ::: "memory");
    __builtin_amdgcn_s_barrier();
    stage(1, BK);

    int cur = 0;
    #pragma unroll 1
    for (int t = 0; t < NSTEP; ++t) {
        #pragma unroll
        for (int kk = 0; kk < 2; ++kk) {
            short8 afr[4], bfr[4];
            #pragma unroll
            for (int mi = 0; mi < 4; ++mi) {
                const int row = wf + mi * 16 + (lane & 15);
                const int kb  = (kk * 64 + ((lane >> 4) << 4)) ^ ((row & 7) << 4);
                afr[mi] = *(const short8*)((const char*)lds_w[cur] + row * 128 + kb);
            }
            #pragma unroll
            for (int ni = 0; ni < 4; ++ni) {
                const int row = wp + ni * 16 + (lane & 15);
                const int kb  = (kk * 64 + ((lane >> 4) << 4)) ^ ((row & 7) << 4);
                bfr[ni] = *(const short8*)((const char*)lds_x[cur] + row * 128 + kb);
            }
            #pragma unroll
            for (int mi = 0; mi < 4; ++mi)
                #pragma unroll
                for (int ni = 0; ni < 4; ++ni)
                    asm("v_mfma_f32_16x16x32_bf16 %0, %1, %2, %0"
                        : "+v"(acc[mi][ni])
                        : "v"(afr[mi]), "v"(bfr[ni]));
        }

        if (t + 2 < NSTEP) {
            __builtin_amdgcn_s_barrier();                    // all done reading buf cur
            stage(cur, (t + 2) * BK);                        // overwrite freed buffer
            asm volatile("s_waitcnt vmcnt(8)" ::: "memory"); // tile t+1 loads done
            __builtin_amdgcn_s_barrier();                    // tile t+1 visible to all
        } else if (t + 1 < NSTEP) {
            asm volatile("s_waitcnt vmcnt(0)" ::: "memory"); // last tile's loads done
            __builtin_amdgcn_s_barrier();
        }
        cur ^= 1;
    }

    // Epilogue: lane holds D[f][p] frag: f = (lane>>4)*4 + r, p = lane&15.
    #pragma unroll
    for (int ni = 0; ni < 4; ++ni) {
        const int pl = wp + ni * 16 + (lane & 15);
        const int p  = p0 + pl;
        if (p >= cnt) continue;
        const float w = wgt_s[pl];
        unsigned short* hr = hpart + (size_t)(e * T_TOKENS + p) * DMODEL + f0 + wf;
        #pragma unroll
        for (int mi = 0; mi < 4; ++mi) {
            const int fb = mi * 16 + ((lane >> 4) << 2);
            const float* ber = be + (size_t)e * DMODEL + f0 + wf + fb;
            ushort4 o;
            float v0 = acc[mi][ni][0] + ber[0]; v0 = v0 > 0.f ? v0 : 0.f;
            float v1 = acc[mi][ni][1] + ber[1]; v1 = v1 > 0.f ? v1 : 0.f;
            float v2 = acc[mi][ni][2] + ber[2]; v2 = v2 > 0.f ? v2 : 0.f;
            float v3 = acc[mi][ni][3] + ber[3]; v3 = v3 > 0.f ? v3 : 0.f;
            o.x = f32_to_bf16(v0 * w);
            o.y = f32_to_bf16(v1 * w);
            o.z = f32_to_bf16(v2 * w);
            o.w = f32_to_bf16(v3 * w);
            *reinterpret_cast<ushort4*>(hr + fb) = o;
        }
    }
}

// ---------------------------------------------------------------------------
// Kernel 4: combine — y[t] = hpart[rows[t][0]] + hpart[rows[t][1]]
// ---------------------------------------------------------------------------
__global__ __launch_bounds__(256)
void combine(const unsigned short* __restrict__ hpart,
             const int* __restrict__ rows,
             float* __restrict__ y) {
    const int t = blockIdx.x;
    const int r0 = rows[t * 2 + 0];
    const int r1 = rows[t * 2 + 1];
    const int f = threadIdx.x * 4;
    ushort4 a = *reinterpret_cast<const ushort4*>(hpart + (size_t)r0 * DMODEL + f);
    ushort4 b = *reinterpret_cast<const ushort4*>(hpart + (size_t)r1 * DMODEL + f);
    float4 o;
    o.x = __builtin_bit_cast(float, (unsigned)a.x << 16) + __builtin_bit_cast(float, (unsigned)b.x << 16);
    o.y = __builtin_bit_cast(float, (unsigned)a.y << 16) + __builtin_bit_cast(float, (unsigned)b.y << 16);
    o.z = __builtin_bit_cast(float, (unsigned)a.z << 16) + __builtin_bit_cast(float, (unsigned)b.z << 16);
    o.w = __builtin_bit_cast(float, (unsigned)a.w << 16) + __builtin_bit_cast(float, (unsigned)b.w << 16);
    *reinterpret_cast<float4*>(y + (size_t)t * DMODEL + f) = o;
}

// ---------------------------------------------------------------------------
extern "C" void kernel_launch(void* const* d_in, const int* in_sizes, int n_in,
                              void* d_out, int out_size, void* d_ws, size_t ws_size,
                              hipStream_t stream) {
    (void)in_sizes; (void)n_in; (void)out_size; (void)ws_size;
    const float* x  = (const float*)d_in[0];
    const float* Wg = (const float*)d_in[1];
    const float* We = (const float*)d_in[2];
    const float* be = (const float*)d_in[3];
    float* y = (float*)d_out;

    char* ws = (char*)d_ws;
    unsigned short* xb     = (unsigned short*)(ws);                       // 16 MB
    unsigned short* wt     = (unsigned short*)(ws + (16u << 20));         // 16 MB
    size_t off = (32u << 20);
    int*   counts    = (int*)(ws + off);    off += 1024;
    int*   chunk_cnt = (int*)(ws + off);    off += 1024;
    int*   toks      = (int*)(ws + off);    off += (size_t)NEXP * T_TOKENS * 4;
    float* wgts      = (float*)(ws + off);  off += (size_t)NEXP * T_TOKENS * 4;
    int*   rows      = (int*)(ws + off);    off += (size_t)T_TOKENS * 2 * 4;
    int*   top_e     = (int*)(ws + off);    off += (size_t)T_TOKENS * 4;
    float* top_w     = (float*)(ws + off);
    unsigned short* hpart = (unsigned short*)(ws + (34u << 20));          // 32 MB

    we_transpose<<<dim3(DMODEL / 64, DMODEL / 64, NEXP), 256, 0, stream>>>(We, wt);
    gating<<<dim3(T_TOKENS / 4), 256, 0, stream>>>(x, Wg, xb, top_e, top_w);
    compact_count<<<dim3(NEXP, 32), 256, 0, stream>>>(top_e, chunk_cnt);
    compact_scatter<<<dim3(NEXP, 32), 256, 0, stream>>>(top_e, top_w, chunk_cnt,
                                                        counts, toks, wgts, rows);
    expert_gemm<<<dim3(T_TOKENS / BM, DMODEL / BN, NEXP), 256, 0, stream>>>(
        xb, wt, be, counts, toks, wgts, hpart);
    combine<<<dim3(T_TOKENS), 256, 0, stream>>>(hpart, rows, y);
}

// Round 5
// 131.484 us; speedup vs baseline: 3.5609x; 1.1001x over previous
//
#include <hip/hip_runtime.h>

#define T_TOKENS 8192
#define DMODEL   1024
#define NEXP     8

#define BM 128   // tokens per tile
#define BN 128   // features per tile
#define BK 64    // k per step
#define NSTEP (DMODEL / BK)

typedef float f32x4  __attribute__((ext_vector_type(4)));
typedef short short8 __attribute__((ext_vector_type(8)));

__device__ __forceinline__ unsigned short f32_to_bf16(float f) {
    unsigned int u = __builtin_bit_cast(unsigned int, f);
    unsigned int r = 0x7FFFu + ((u >> 16) & 1u);
    return (unsigned short)((u + r) >> 16);
}

// ---------------------------------------------------------------------------
// Kernel 1: We [E][d][f] fp32  ->  we_t [E][f][d] bf16 (LDS-tiled transpose)
// ---------------------------------------------------------------------------
__global__ __launch_bounds__(256)
void we_transpose(const float* __restrict__ We, unsigned short* __restrict__ wt) {
    __shared__ unsigned short tile[64][72];
    const int e  = blockIdx.z;
    const int d0 = blockIdx.x * 64;
    const int f0 = blockIdx.y * 64;
    const float* src = We + ((size_t)e * DMODEL + d0) * DMODEL + f0;
    #pragma unroll
    for (int i = 0; i < 16; ++i) {
        int idx = i * 256 + threadIdx.x;
        int dl = idx >> 6, fl = idx & 63;
        tile[fl][dl] = f32_to_bf16(src[(size_t)dl * DMODEL + fl]);
    }
    __syncthreads();
    unsigned short* dst = wt + ((size_t)e * DMODEL + f0) * DMODEL + d0;
    #pragma unroll
    for (int i = 0; i < 16; ++i) {
        int idx = i * 256 + threadIdx.x;
        int fl = idx >> 6, dl = idx & 63;
        dst[(size_t)fl * DMODEL + dl] = tile[fl][dl];
    }
}

// ---------------------------------------------------------------------------
// Kernel 2: gating — fp32 logits + top-2 per token, NO atomics.
// Writes top_e[t] = e1 | (e2<<4) and top_w[t] = w1 (w2 = 1 - w1); x -> bf16.
// ---------------------------------------------------------------------------
__global__ __launch_bounds__(256)
void gating(const float* __restrict__ x, const float* __restrict__ Wg,
            unsigned short* __restrict__ xb,
            int* __restrict__ top_e, float* __restrict__ top_w) {
    const int wave = threadIdx.x >> 6;
    const int lane = threadIdx.x & 63;
    const int t = blockIdx.x * 4 + wave;

    float lg[8];
    #pragma unroll
    for (int e = 0; e < 8; ++e) lg[e] = 0.0f;

    const float* xr = x + (size_t)t * DMODEL;
    unsigned short* xo = xb + (size_t)t * DMODEL;

    #pragma unroll
    for (int j = 0; j < 4; ++j) {
        const int d = j * 256 + lane * 4;
        float4 xv = *reinterpret_cast<const float4*>(xr + d);
        ushort4 o;
        o.x = f32_to_bf16(xv.x);
        o.y = f32_to_bf16(xv.y);
        o.z = f32_to_bf16(xv.z);
        o.w = f32_to_bf16(xv.w);
        *reinterpret_cast<ushort4*>(xo + d) = o;
        const float xs[4] = {xv.x, xv.y, xv.z, xv.w};
        #pragma unroll
        for (int c = 0; c < 4; ++c) {
            const float4 wlo = *reinterpret_cast<const float4*>(Wg + (size_t)(d + c) * 8);
            const float4 whi = *reinterpret_cast<const float4*>(Wg + (size_t)(d + c) * 8 + 4);
            lg[0] += xs[c] * wlo.x;  lg[1] += xs[c] * wlo.y;
            lg[2] += xs[c] * wlo.z;  lg[3] += xs[c] * wlo.w;
            lg[4] += xs[c] * whi.x;  lg[5] += xs[c] * whi.y;
            lg[6] += xs[c] * whi.z;  lg[7] += xs[c] * whi.w;
        }
    }
    #pragma unroll
    for (int off = 1; off < 64; off <<= 1) {
        #pragma unroll
        for (int e = 0; e < 8; ++e) lg[e] += __shfl_xor(lg[e], off);
    }

    if (lane == 0) {
        int i1 = 0; float v1 = lg[0];
        #pragma unroll
        for (int e = 1; e < 8; ++e) if (lg[e] > v1) { v1 = lg[e]; i1 = e; }
        int i2 = -1; float v2 = -1e30f;
        #pragma unroll
        for (int e = 0; e < 8; ++e) if (e != i1 && lg[e] > v2) { v2 = lg[e]; i2 = e; }
        const float w1 = 1.0f / (1.0f + __expf(v2 - v1));
        top_e[t] = i1 | (i2 << 4);
        top_w[t] = w1;
    }
}

// ---------------------------------------------------------------------------
// Kernel 2b: compact_count — grid (E, 32). Block (e,c) counts matches of
// expert e among tokens [c*256, c*256+256). No atomics.
// ---------------------------------------------------------------------------
__global__ __launch_bounds__(256)
void compact_count(const int* __restrict__ top_e, int* __restrict__ chunk_cnt) {
    const int e = blockIdx.x, c = blockIdx.y;
    const int t = c * 256 + threadIdx.x;
    const int te = top_e[t];
    const bool m = ((te & 15) == e) || (((te >> 4) & 15) == e);
    __shared__ int ws[4];
    unsigned long long b = __ballot(m);
    if ((threadIdx.x & 63) == 0) ws[threadIdx.x >> 6] = __popcll(b);
    __syncthreads();
    if (threadIdx.x == 0)
        chunk_cnt[e * 32 + c] = ws[0] + ws[1] + ws[2] + ws[3];
}

// ---------------------------------------------------------------------------
// Kernel 2c: compact_scatter — grid (E, 32). Inline exclusive prefix over
// chunk counts, ballot-ordered scatter. Deterministic, zero atomics.
// ---------------------------------------------------------------------------
__global__ __launch_bounds__(256)
void compact_scatter(const int* __restrict__ top_e, const float* __restrict__ top_w,
                     const int* __restrict__ chunk_cnt,
                     int* __restrict__ counts, int* __restrict__ toks,
                     float* __restrict__ wgts, int* __restrict__ rows) {
    const int e    = blockIdx.x;
    const int c    = blockIdx.y;
    const int tid  = threadIdx.x;
    const int wave = tid >> 6;
    const int lane = tid & 63;

    __shared__ int sc[32];
    __shared__ int ws[4];
    if (tid < 32) sc[tid] = chunk_cnt[e * 32 + tid];

    const int t  = c * 256 + tid;
    const int te = top_e[t];
    const int e1 = te & 15;
    const int e2 = (te >> 4) & 15;
    const bool m = (e1 == e) || (e2 == e);
    const unsigned long long b = __ballot(m);
    const int pos_in_wave = __popcll(b & ((1ull << lane) - 1ull));
    if (lane == 0) ws[wave] = __popcll(b);
    __syncthreads();

    int base = 0;
    for (int i = 0; i < c; ++i) base += sc[i];
    int woff = base;
    #pragma unroll
    for (int i = 0; i < 4; ++i) if (i < wave) woff += ws[i];

    if (m) {
        const int pos = woff + pos_in_wave;
        const float w1 = top_w[t];
        toks[e * T_TOKENS + pos] = t;
        wgts[e * T_TOKENS + pos] = (e1 == e) ? w1 : 1.0f - w1;
        rows[t * 2 + ((e1 == e) ? 0 : 1)] = e * T_TOKENS + pos;
    }
    if (c == 31 && tid == 0)
        counts[e] = base + ws[0] + ws[1] + ws[2] + ws[3];
}

// ---------------------------------------------------------------------------
// Kernel 3: per-expert gather-GEMM, m97 structure: SINGLE-buffered 32 KB LDS
// (33.8 KB total -> 4 blocks/CU, 16 waves/CU), 2 barriers per K-step, TLP
// hides latency. The r4 double-buffer (66.5 KB) capped residency at ~1
// block/CU (Occupancy 10.9%) so no wave overlap existed at all — both naive
// and counted-vmcnt schedules sat at the same latency-exposed 94 us.
//   D[f][p] = sum_k we_t[e][f][k] * x[tok[p]][k]
// ---------------------------------------------------------------------------
__global__ __launch_bounds__(256)
void expert_gemm(const unsigned short* __restrict__ xb,
                 const unsigned short* __restrict__ wt,
                 const float* __restrict__ be,
                 const int* __restrict__ counts,
                 const int* __restrict__ toks,
                 const float* __restrict__ wgts,
                 unsigned short* __restrict__ hpart) {
    const int e   = blockIdx.z;
    const int cnt = counts[e];
    const int p0  = blockIdx.x * BM;
    if (p0 >= cnt) return;
    const int f0  = blockIdx.y * BN;

    __shared__ unsigned short lds_w[BN * BK];  // [f][k], swizzled, 16 KB
    __shared__ unsigned short lds_x[BM * BK];  // [p][k], swizzled, 16 KB
    __shared__ int   tok_s[BM];
    __shared__ float wgt_s[BM];

    const int tid  = threadIdx.x;
    const int wave = tid >> 6;
    const int lane = tid & 63;

    if (tid < BM) {
        int p = p0 + tid;
        if (p < cnt) {
            tok_s[tid] = toks[e * T_TOKENS + p];
            wgt_s[tid] = wgts[e * T_TOKENS + p];
        } else {
            tok_s[tid] = 0;
            wgt_s[tid] = 0.0f;
        }
    }
    __syncthreads();

    // Per-lane staging sources, pre-swizzled so the linear global_load_lds
    // write produces the XOR-swizzled LDS layout.
    const char* wsrc[4];
    const char* xsrc[4];
    #pragma unroll
    for (int s = 0; s < 4; ++s) {
        const int q    = wave * 4 + s;
        const int row  = q * 8 + (lane >> 3);
        const int scol = ((lane & 7) << 4) ^ ((row & 7) << 4);
        wsrc[s] = (const char*)wt + ((size_t)(e * DMODEL + f0 + row) * DMODEL) * 2 + scol;
        xsrc[s] = (const char*)xb + ((size_t)tok_s[row] * DMODEL) * 2 + scol;
    }

    f32x4 acc[4][4] = {};

    const int wf = (wave & 1) * 64;   // feature sub-block of this wave
    const int wp = (wave >> 1) * 64;  // token sub-block of this wave

    #pragma unroll 1
    for (int t = 0; t < NSTEP; ++t) {
        const size_t ko = (size_t)t * BK * 2;
        #pragma unroll
        for (int s = 0; s < 4; ++s) {
            __builtin_amdgcn_global_load_lds(
                (const __attribute__((address_space(1))) void*)(wsrc[s] + ko),
                (__attribute__((address_space(3))) void*)((char*)lds_w + (wave * 4 + s) * 1024),
                16, 0, 0);
            __builtin_amdgcn_global_load_lds(
                (const __attribute__((address_space(1))) void*)(xsrc[s] + ko),
                (__attribute__((address_space(3))) void*)((char*)lds_x + (wave * 4 + s) * 1024),
                16, 0, 0);
        }
        __syncthreads();   // drains vmcnt -> tile visible to all waves

        #pragma unroll
        for (int kk = 0; kk < 2; ++kk) {
            short8 afr[4], bfr[4];
            #pragma unroll
            for (int mi = 0; mi < 4; ++mi) {
                const int row = wf + mi * 16 + (lane & 15);
                const int kb  = (kk * 64 + ((lane >> 4) << 4)) ^ ((row & 7) << 4);
                afr[mi] = *(const short8*)((const char*)lds_w + row * 128 + kb);
            }
            #pragma unroll
            for (int ni = 0; ni < 4; ++ni) {
                const int row = wp + ni * 16 + (lane & 15);
                const int kb  = (kk * 64 + ((lane >> 4) << 4)) ^ ((row & 7) << 4);
                bfr[ni] = *(const short8*)((const char*)lds_x + row * 128 + kb);
            }
            #pragma unroll
            for (int mi = 0; mi < 4; ++mi)
                #pragma unroll
                for (int ni = 0; ni < 4; ++ni)
                    asm("v_mfma_f32_16x16x32_bf16 %0, %1, %2, %0"
                        : "+v"(acc[mi][ni])
                        : "v"(afr[mi]), "v"(bfr[ni]));
        }
        __syncthreads();   // all waves done reading before next overwrite
    }

    // Epilogue: lane holds D[f][p] frag: f = (lane>>4)*4 + r, p = lane&15.
    #pragma unroll
    for (int ni = 0; ni < 4; ++ni) {
        const int pl = wp + ni * 16 + (lane & 15);
        const int p  = p0 + pl;
        if (p >= cnt) continue;
        const float w = wgt_s[pl];
        unsigned short* hr = hpart + (size_t)(e * T_TOKENS + p) * DMODEL + f0 + wf;
        #pragma unroll
        for (int mi = 0; mi < 4; ++mi) {
            const int fb = mi * 16 + ((lane >> 4) << 2);
            const float* ber = be + (size_t)e * DMODEL + f0 + wf + fb;
            ushort4 o;
            float v0 = acc[mi][ni][0] + ber[0]; v0 = v0 > 0.f ? v0 : 0.f;
            float v1 = acc[mi][ni][1] + ber[1]; v1 = v1 > 0.f ? v1 : 0.f;
            float v2 = acc[mi][ni][2] + ber[2]; v2 = v2 > 0.f ? v2 : 0.f;
            float v3 = acc[mi][ni][3] + ber[3]; v3 = v3 > 0.f ? v3 : 0.f;
            o.x = f32_to_bf16(v0 * w);
            o.y = f32_to_bf16(v1 * w);
            o.z = f32_to_bf16(v2 * w);
            o.w = f32_to_bf16(v3 * w);
            *reinterpret_cast<ushort4*>(hr + fb) = o;
        }
    }
}

// ---------------------------------------------------------------------------
// Kernel 4: combine — y[t] = hpart[rows[t][0]] + hpart[rows[t][1]]
// ---------------------------------------------------------------------------
__global__ __launch_bounds__(256)
void combine(const unsigned short* __restrict__ hpart,
             const int* __restrict__ rows,
             float* __restrict__ y) {
    const int t = blockIdx.x;
    const int r0 = rows[t * 2 + 0];
    const int r1 = rows[t * 2 + 1];
    const int f = threadIdx.x * 4;
    ushort4 a = *reinterpret_cast<const ushort4*>(hpart + (size_t)r0 * DMODEL + f);
    ushort4 b = *reinterpret_cast<const ushort4*>(hpart + (size_t)r1 * DMODEL + f);
    float4 o;
    o.x = __builtin_bit_cast(float, (unsigned)a.x << 16) + __builtin_bit_cast(float, (unsigned)b.x << 16);
    o.y = __builtin_bit_cast(float, (unsigned)a.y << 16) + __builtin_bit_cast(float, (unsigned)b.y << 16);
    o.z = __builtin_bit_cast(float, (unsigned)a.z << 16) + __builtin_bit_cast(float, (unsigned)b.z << 16);
    o.w = __builtin_bit_cast(float, (unsigned)a.w << 16) + __builtin_bit_cast(float, (unsigned)b.w << 16);
    *reinterpret_cast<float4*>(y + (size_t)t * DMODEL + f) = o;
}

// ---------------------------------------------------------------------------
extern "C" void kernel_launch(void* const* d_in, const int* in_sizes, int n_in,
                              void* d_out, int out_size, void* d_ws, size_t ws_size,
                              hipStream_t stream) {
    (void)in_sizes; (void)n_in; (void)out_size; (void)ws_size;
    const float* x  = (const float*)d_in[0];
    const float* Wg = (const float*)d_in[1];
    const float* We = (const float*)d_in[2];
    const float* be = (const float*)d_in[3];
    float* y = (float*)d_out;

    char* ws = (char*)d_ws;
    unsigned short* xb     = (unsigned short*)(ws);                       // 16 MB
    unsigned short* wt     = (unsigned short*)(ws + (16u << 20));         // 16 MB
    size_t off = (32u << 20);
    int*   counts    = (int*)(ws + off);    off += 1024;
    int*   chunk_cnt = (int*)(ws + off);    off += 1024;
    int*   toks      = (int*)(ws + off);    off += (size_t)NEXP * T_TOKENS * 4;
    float* wgts      = (float*)(ws + off);  off += (size_t)NEXP * T_TOKENS * 4;
    int*   rows      = (int*)(ws + off);    off += (size_t)T_TOKENS * 2 * 4;
    int*   top_e     = (int*)(ws + off);    off += (size_t)T_TOKENS * 4;
    float* top_w     = (float*)(ws + off);
    unsigned short* hpart = (unsigned short*)(ws + (34u << 20));          // 32 MB

    we_transpose<<<dim3(DMODEL / 64, DMODEL / 64, NEXP), 256, 0, stream>>>(We, wt);
    gating<<<dim3(T_TOKENS / 4), 256, 0, stream>>>(x, Wg, xb, top_e, top_w);
    compact_count<<<dim3(NEXP, 32), 256, 0, stream>>>(top_e, chunk_cnt);
    compact_scatter<<<dim3(NEXP, 32), 256, 0, stream>>>(top_e, top_w, chunk_cnt,
                                                        counts, toks, wgts, rows);
    expert_gemm<<<dim3(T_TOKENS / BM, DMODEL / BN, NEXP), 256, 0, stream>>>(
        xb, wt, be, counts, toks, wgts, hpart);
    combine<<<dim3(T_TOKENS), 256, 0, stream>>>(hpart, rows, y);
}

// Round 6
// 117.794 us; speedup vs baseline: 3.9748x; 1.1162x over previous
//
#include <hip/hip_runtime.h>

#define T_TOKENS 8192
#define DMODEL   1024
#define NEXP     8

#define BM 128   // tokens per tile
#define BN 128   // features per tile
#define BK 64    // k per step
#define NSTEP (DMODEL / BK)

typedef float f32x4  __attribute__((ext_vector_type(4)));
typedef short short8 __attribute__((ext_vector_type(8)));

__device__ __forceinline__ unsigned short f32_to_bf16(float f) {
    unsigned int u = __builtin_bit_cast(unsigned int, f);
    unsigned int r = 0x7FFFu + ((u >> 16) & 1u);
    return (unsigned short)((u + r) >> 16);
}

// ---------------------------------------------------------------------------
// Kernel 1: We [E][d][f] fp32  ->  we_t [E][f][d] bf16 (LDS-tiled transpose)
// ---------------------------------------------------------------------------
__global__ __launch_bounds__(256)
void we_transpose(const float* __restrict__ We, unsigned short* __restrict__ wt) {
    __shared__ unsigned short tile[64][72];
    const int e  = blockIdx.z;
    const int d0 = blockIdx.x * 64;
    const int f0 = blockIdx.y * 64;
    const float* src = We + ((size_t)e * DMODEL + d0) * DMODEL + f0;
    #pragma unroll
    for (int i = 0; i < 16; ++i) {
        int idx = i * 256 + threadIdx.x;
        int dl = idx >> 6, fl = idx & 63;
        tile[fl][dl] = f32_to_bf16(src[(size_t)dl * DMODEL + fl]);
    }
    __syncthreads();
    unsigned short* dst = wt + ((size_t)e * DMODEL + f0) * DMODEL + d0;
    #pragma unroll
    for (int i = 0; i < 16; ++i) {
        int idx = i * 256 + threadIdx.x;
        int fl = idx >> 6, dl = idx & 63;
        dst[(size_t)fl * DMODEL + dl] = tile[fl][dl];
    }
}

// ---------------------------------------------------------------------------
// Kernel 2: gating — fp32 logits + top-2 per token, NO atomics.
// Writes top_e[t] = e1 | (e2<<4) and top_w[t] = w1 (w2 = 1 - w1); x -> bf16.
// ---------------------------------------------------------------------------
__global__ __launch_bounds__(256)
void gating(const float* __restrict__ x, const float* __restrict__ Wg,
            unsigned short* __restrict__ xb,
            int* __restrict__ top_e, float* __restrict__ top_w) {
    const int wave = threadIdx.x >> 6;
    const int lane = threadIdx.x & 63;
    const int t = blockIdx.x * 4 + wave;

    float lg[8];
    #pragma unroll
    for (int e = 0; e < 8; ++e) lg[e] = 0.0f;

    const float* xr = x + (size_t)t * DMODEL;
    unsigned short* xo = xb + (size_t)t * DMODEL;

    #pragma unroll
    for (int j = 0; j < 4; ++j) {
        const int d = j * 256 + lane * 4;
        float4 xv = *reinterpret_cast<const float4*>(xr + d);
        ushort4 o;
        o.x = f32_to_bf16(xv.x);
        o.y = f32_to_bf16(xv.y);
        o.z = f32_to_bf16(xv.z);
        o.w = f32_to_bf16(xv.w);
        *reinterpret_cast<ushort4*>(xo + d) = o;
        const float xs[4] = {xv.x, xv.y, xv.z, xv.w};
        #pragma unroll
        for (int c = 0; c < 4; ++c) {
            const float4 wlo = *reinterpret_cast<const float4*>(Wg + (size_t)(d + c) * 8);
            const float4 whi = *reinterpret_cast<const float4*>(Wg + (size_t)(d + c) * 8 + 4);
            lg[0] += xs[c] * wlo.x;  lg[1] += xs[c] * wlo.y;
            lg[2] += xs[c] * wlo.z;  lg[3] += xs[c] * wlo.w;
            lg[4] += xs[c] * whi.x;  lg[5] += xs[c] * whi.y;
            lg[6] += xs[c] * whi.z;  lg[7] += xs[c] * whi.w;
        }
    }
    #pragma unroll
    for (int off = 1; off < 64; off <<= 1) {
        #pragma unroll
        for (int e = 0; e < 8; ++e) lg[e] += __shfl_xor(lg[e], off);
    }

    if (lane == 0) {
        int i1 = 0; float v1 = lg[0];
        #pragma unroll
        for (int e = 1; e < 8; ++e) if (lg[e] > v1) { v1 = lg[e]; i1 = e; }
        int i2 = -1; float v2 = -1e30f;
        #pragma unroll
        for (int e = 0; e < 8; ++e) if (e != i1 && lg[e] > v2) { v2 = lg[e]; i2 = e; }
        const float w1 = 1.0f / (1.0f + __expf(v2 - v1));
        top_e[t] = i1 | (i2 << 4);
        top_w[t] = w1;
    }
}

// ---------------------------------------------------------------------------
// Kernel 2b: compact_count — grid (E, 32). Block (e,c) counts matches of
// expert e among tokens [c*256, c*256+256). No atomics.
// ---------------------------------------------------------------------------
__global__ __launch_bounds__(256)
void compact_count(const int* __restrict__ top_e, int* __restrict__ chunk_cnt) {
    const int e = blockIdx.x, c = blockIdx.y;
    const int t = c * 256 + threadIdx.x;
    const int te = top_e[t];
    const bool m = ((te & 15) == e) || (((te >> 4) & 15) == e);
    __shared__ int ws[4];
    unsigned long long b = __ballot(m);
    if ((threadIdx.x & 63) == 0) ws[threadIdx.x >> 6] = __popcll(b);
    __syncthreads();
    if (threadIdx.x == 0)
        chunk_cnt[e * 32 + c] = ws[0] + ws[1] + ws[2] + ws[3];
}

// ---------------------------------------------------------------------------
// Kernel 2c: compact_scatter — grid (E, 32). Inline exclusive prefix over
// chunk counts, ballot-ordered scatter. Deterministic, zero atomics.
// ---------------------------------------------------------------------------
__global__ __launch_bounds__(256)
void compact_scatter(const int* __restrict__ top_e, const float* __restrict__ top_w,
                     const int* __restrict__ chunk_cnt,
                     int* __restrict__ counts, int* __restrict__ toks,
                     float* __restrict__ wgts, int* __restrict__ rows) {
    const int e    = blockIdx.x;
    const int c    = blockIdx.y;
    const int tid  = threadIdx.x;
    const int wave = tid >> 6;
    const int lane = tid & 63;

    __shared__ int sc[32];
    __shared__ int ws[4];
    if (tid < 32) sc[tid] = chunk_cnt[e * 32 + tid];

    const int t  = c * 256 + tid;
    const int te = top_e[t];
    const int e1 = te & 15;
    const int e2 = (te >> 4) & 15;
    const bool m = (e1 == e) || (e2 == e);
    const unsigned long long b = __ballot(m);
    const int pos_in_wave = __popcll(b & ((1ull << lane) - 1ull));
    if (lane == 0) ws[wave] = __popcll(b);
    __syncthreads();

    int base = 0;
    for (int i = 0; i < c; ++i) base += sc[i];
    int woff = base;
    #pragma unroll
    for (int i = 0; i < 4; ++i) if (i < wave) woff += ws[i];

    if (m) {
        const int pos = woff + pos_in_wave;
        const float w1 = top_w[t];
        toks[e * T_TOKENS + pos] = t;
        wgts[e * T_TOKENS + pos] = (e1 == e) ? w1 : 1.0f - w1;
        rows[t * 2 + ((e1 == e) ? 0 : 1)] = e * T_TOKENS + pos;
    }
    if (c == 31 && tid == 0)
        counts[e] = base + ws[0] + ws[1] + ws[2] + ws[3];
}

// ---------------------------------------------------------------------------
// Kernel 3: per-expert gather-GEMM (m97 structure, single 32 KB buffer)
// with f-tile -> XCD dispatch remap:
//   flat dispatch id; fy = flat % 8 (HW round-robins consecutive workgroups
//   across the 8 XCDs, so each XCD sees ONE feature slice). Per (XCD, expert)
//   the wt working set is 128 f-rows x 1024 k x 2B = 256 KB -> permanently
//   L2-resident, fetched once (16 MB total vs r5's 83 MB FETCH). Work is
//   perfectly balanced: every XCD processes every expert's token tiles.
//   D[f][p] = sum_k we_t[e][f][k] * x[tok[p]][k]
// ---------------------------------------------------------------------------
__global__ __launch_bounds__(256)
void expert_gemm(const unsigned short* __restrict__ xb,
                 const unsigned short* __restrict__ wt,
                 const float* __restrict__ be,
                 const int* __restrict__ counts,
                 const int* __restrict__ toks,
                 const float* __restrict__ wgts,
                 unsigned short* __restrict__ hpart) {
    // --- XCD-aware remap (bijective on the 64x8x8 grid) ---
    const int flat = blockIdx.x + 64 * (blockIdx.y + 8 * blockIdx.z);
    const int fy   = flat & 7;          // feature tile: constant per XCD
    const int rest = flat >> 3;
    const int tx   = rest & 63;         // token tile: advances in lockstep
    const int e    = rest >> 6;         // expert: outermost

    const int cnt = counts[e];
    const int p0  = tx * BM;
    if (p0 >= cnt) return;
    const int f0  = fy * BN;

    __shared__ unsigned short lds_w[BN * BK];  // [f][k], swizzled, 16 KB
    __shared__ unsigned short lds_x[BM * BK];  // [p][k], swizzled, 16 KB
    __shared__ int   tok_s[BM];
    __shared__ float wgt_s[BM];

    const int tid  = threadIdx.x;
    const int wave = tid >> 6;
    const int lane = tid & 63;

    if (tid < BM) {
        int p = p0 + tid;
        if (p < cnt) {
            tok_s[tid] = toks[e * T_TOKENS + p];
            wgt_s[tid] = wgts[e * T_TOKENS + p];
        } else {
            tok_s[tid] = 0;
            wgt_s[tid] = 0.0f;
        }
    }
    __syncthreads();

    // Per-lane staging sources, pre-swizzled so the linear global_load_lds
    // write produces the XOR-swizzled LDS layout.
    const char* wsrc[4];
    const char* xsrc[4];
    #pragma unroll
    for (int s = 0; s < 4; ++s) {
        const int q    = wave * 4 + s;
        const int row  = q * 8 + (lane >> 3);
        const int scol = ((lane & 7) << 4) ^ ((row & 7) << 4);
        wsrc[s] = (const char*)wt + ((size_t)(e * DMODEL + f0 + row) * DMODEL) * 2 + scol;
        xsrc[s] = (const char*)xb + ((size_t)tok_s[row] * DMODEL) * 2 + scol;
    }

    f32x4 acc[4][4] = {};

    const int wf = (wave & 1) * 64;   // feature sub-block of this wave
    const int wp = (wave >> 1) * 64;  // token sub-block of this wave

    #pragma unroll 1
    for (int t = 0; t < NSTEP; ++t) {
        const size_t ko = (size_t)t * BK * 2;
        #pragma unroll
        for (int s = 0; s < 4; ++s) {
            __builtin_amdgcn_global_load_lds(
                (const __attribute__((address_space(1))) void*)(wsrc[s] + ko),
                (__attribute__((address_space(3))) void*)((char*)lds_w + (wave * 4 + s) * 1024),
                16, 0, 0);
            __builtin_amdgcn_global_load_lds(
                (const __attribute__((address_space(1))) void*)(xsrc[s] + ko),
                (__attribute__((address_space(3))) void*)((char*)lds_x + (wave * 4 + s) * 1024),
                16, 0, 0);
        }
        __syncthreads();   // drains vmcnt -> tile visible to all waves

        #pragma unroll
        for (int kk = 0; kk < 2; ++kk) {
            short8 afr[4], bfr[4];
            #pragma unroll
            for (int mi = 0; mi < 4; ++mi) {
                const int row = wf + mi * 16 + (lane & 15);
                const int kb  = (kk * 64 + ((lane >> 4) << 4)) ^ ((row & 7) << 4);
                afr[mi] = *(const short8*)((const char*)lds_w + row * 128 + kb);
            }
            #pragma unroll
            for (int ni = 0; ni < 4; ++ni) {
                const int row = wp + ni * 16 + (lane & 15);
                const int kb  = (kk * 64 + ((lane >> 4) << 4)) ^ ((row & 7) << 4);
                bfr[ni] = *(const short8*)((const char*)lds_x + row * 128 + kb);
            }
            #pragma unroll
            for (int mi = 0; mi < 4; ++mi)
                #pragma unroll
                for (int ni = 0; ni < 4; ++ni)
                    asm("v_mfma_f32_16x16x32_bf16 %0, %1, %2, %0"
                        : "+v"(acc[mi][ni])
                        : "v"(afr[mi]), "v"(bfr[ni]));
        }
        __syncthreads();   // all waves done reading before next overwrite
    }

    // Epilogue: lane holds D[f][p] frag: f = (lane>>4)*4 + r, p = lane&15.
    #pragma unroll
    for (int ni = 0; ni < 4; ++ni) {
        const int pl = wp + ni * 16 + (lane & 15);
        const int p  = p0 + pl;
        if (p >= cnt) continue;
        const float w = wgt_s[pl];
        unsigned short* hr = hpart + (size_t)(e * T_TOKENS + p) * DMODEL + f0 + wf;
        #pragma unroll
        for (int mi = 0; mi < 4; ++mi) {
            const int fb = mi * 16 + ((lane >> 4) << 2);
            const float* ber = be + (size_t)e * DMODEL + f0 + wf + fb;
            ushort4 o;
            float v0 = acc[mi][ni][0] + ber[0]; v0 = v0 > 0.f ? v0 : 0.f;
            float v1 = acc[mi][ni][1] + ber[1]; v1 = v1 > 0.f ? v1 : 0.f;
            float v2 = acc[mi][ni][2] + ber[2]; v2 = v2 > 0.f ? v2 : 0.f;
            float v3 = acc[mi][ni][3] + ber[3]; v3 = v3 > 0.f ? v3 : 0.f;
            o.x = f32_to_bf16(v0 * w);
            o.y = f32_to_bf16(v1 * w);
            o.z = f32_to_bf16(v2 * w);
            o.w = f32_to_bf16(v3 * w);
            *reinterpret_cast<ushort4*>(hr + fb) = o;
        }
    }
}

// ---------------------------------------------------------------------------
// Kernel 4: combine — y[t] = hpart[rows[t][0]] + hpart[rows[t][1]]
// ---------------------------------------------------------------------------
__global__ __launch_bounds__(256)
void combine(const unsigned short* __restrict__ hpart,
             const int* __restrict__ rows,
             float* __restrict__ y) {
    const int t = blockIdx.x;
    const int r0 = rows[t * 2 + 0];
    const int r1 = rows[t * 2 + 1];
    const int f = threadIdx.x * 4;
    ushort4 a = *reinterpret_cast<const ushort4*>(hpart + (size_t)r0 * DMODEL + f);
    ushort4 b = *reinterpret_cast<const ushort4*>(hpart + (size_t)r1 * DMODEL + f);
    float4 o;
    o.x = __builtin_bit_cast(float, (unsigned)a.x << 16) + __builtin_bit_cast(float, (unsigned)b.x << 16);
    o.y = __builtin_bit_cast(float, (unsigned)a.y << 16) + __builtin_bit_cast(float, (unsigned)b.y << 16);
    o.z = __builtin_bit_cast(float, (unsigned)a.z << 16) + __builtin_bit_cast(float, (unsigned)b.z << 16);
    o.w = __builtin_bit_cast(float, (unsigned)a.w << 16) + __builtin_bit_cast(float, (unsigned)b.w << 16);
    *reinterpret_cast<float4*>(y + (size_t)t * DMODEL + f) = o;
}

// ---------------------------------------------------------------------------
extern "C" void kernel_launch(void* const* d_in, const int* in_sizes, int n_in,
                              void* d_out, int out_size, void* d_ws, size_t ws_size,
                              hipStream_t stream) {
    (void)in_sizes; (void)n_in; (void)out_size; (void)ws_size;
    const float* x  = (const float*)d_in[0];
    const float* Wg = (const float*)d_in[1];
    const float* We = (const float*)d_in[2];
    const float* be = (const float*)d_in[3];
    float* y = (float*)d_out;

    char* ws = (char*)d_ws;
    unsigned short* xb     = (unsigned short*)(ws);                       // 16 MB
    unsigned short* wt     = (unsigned short*)(ws + (16u << 20));         // 16 MB
    size_t off = (32u << 20);
    int*   counts    = (int*)(ws + off);    off += 1024;
    int*   chunk_cnt = (int*)(ws + off);    off += 1024;
    int*   toks      = (int*)(ws + off);    off += (size_t)NEXP * T_TOKENS * 4;
    float* wgts      = (float*)(ws + off);  off += (size_t)NEXP * T_TOKENS * 4;
    int*   rows      = (int*)(ws + off);    off += (size_t)T_TOKENS * 2 * 4;
    int*   top_e     = (int*)(ws + off);    off += (size_t)T_TOKENS * 4;
    float* top_w     = (float*)(ws + off);
    unsigned short* hpart = (unsigned short*)(ws + (34u << 20));          // 32 MB

    we_transpose<<<dim3(DMODEL / 64, DMODEL / 64, NEXP), 256, 0, stream>>>(We, wt);
    gating<<<dim3(T_TOKENS / 4), 256, 0, stream>>>(x, Wg, xb, top_e, top_w);
    compact_count<<<dim3(NEXP, 32), 256, 0, stream>>>(top_e, chunk_cnt);
    compact_scatter<<<dim3(NEXP, 32), 256, 0, stream>>>(top_e, top_w, chunk_cnt,
                                                        counts, toks, wgts, rows);
    expert_gemm<<<dim3(T_TOKENS / BM, DMODEL / BN, NEXP), 256, 0, stream>>>(
        xb, wt, be, counts, toks, wgts, hpart);
    combine<<<dim3(T_TOKENS), 256, 0, stream>>>(hpart, rows, y);
}